// Round 3
// baseline (239.068 us; speedup 1.0000x reference)
//
#include <hip/hip_runtime.h>

// LinearKoopmanLayer: out[b,2f,t]   = c*x[b,2f,t] - s*x[b,2f+1,t]
//                     out[b,2f+1,t] = s*x[b,2f,t] + c*x[b,2f+1,t]
// a = amp[f]^dt[b], c = a*cos(freq[f]*dt[b]), s = a*sin(freq[f]*dt[b]).
//
// R3: persistent-loop restructure. R0/R1/R2 (one-shot blocks, 16384 or
// 4096 of them) were all ~80.7 us at 2.5-3.3 TB/s with every pipe idle
// (VALUBusy 3.4%, occupancy 62%) -> block-churn / one-shot-wave limited,
// not bandwidth limited. The rocclr fill kernels in the same capture
// sustain 6.7 TB/s at 9.5% occupancy via long-lived looping waves.
// This version adopts that regime: 2048 blocks (exactly 8 per CU, no
// churn, no tail), each block loops over ITERS=8 (b,f) row-pairs with a
// 2-stage software pipeline (iteration j+1's loads issued before
// iteration j's compute+store), so each wave keeps a continuous rolling
// load stream like m13's 6.29 TB/s copy kernel.
// Coefficients are recomputed per iteration as scalars (no runtime-
// indexed register arrays -> no scratch). Stores are nontemporal (output
// is never re-read); loads are plain (input half-hits L3 fill residue:
// FETCH_SIZE was 65.5 MB of a 134 MB input).

constexpr int Bn = 256;
constexpr int Fn = 64;
constexpr int Tn = 1024;
constexpr int ITERS = 8;                     // bf row-pairs per block
constexpr int GRID  = Bn * Fn / ITERS;       // 2048 blocks = 8 per CU

typedef float v4f __attribute__((ext_vector_type(4)));

__global__ __launch_bounds__(256) void koopman_kernel(
    const float* __restrict__ x,
    const float* __restrict__ delta_t,
    const float* __restrict__ amplitudes,
    const float* __restrict__ frequencies,
    float* __restrict__ out) {
    const int t      = threadIdx.x;          // 0..255 covers Tn/4 v4f
    const int bfBase = blockIdx.x * ITERS;

    // Each bf pair is a contiguous 2048-float (512 v4f) region:
    //   [0,256) v4f = row 2f (x0), [256,512) v4f = row 2f+1 (x1).
    const v4f* __restrict__ xp = reinterpret_cast<const v4f*>(x)
                               + (size_t)bfBase * 512;
    v4f*       __restrict__ op = reinterpret_cast<v4f*>(out)
                               + (size_t)bfBase * 512;

    // Stage 0 of the pipeline: preload iteration 0.
    v4f a0 = xp[t];
    v4f a1 = xp[t + 256];

#pragma unroll 2
    for (int j = 0; j < ITERS; ++j) {
        // Issue next iteration's loads before touching this iteration's
        // data: keeps a rolling 2 KiB/wave read stream in flight.
        v4f n0, n1;
        if (j + 1 < ITERS) {
            n0 = xp[(j + 1) * 512 + t];
            n1 = xp[(j + 1) * 512 + 256 + t];
        }

        // Wave-uniform coefficients via native transcendentals
        // (v_sin/v_cos take revolutions, hence the 1/2pi scale).
        const int bf = bfBase + j;
        const int b  = bf >> 6;              // F = 64
        const int f  = bf & 63;
        const float d = delta_t[b];
        const float a = __builtin_amdgcn_exp2f(d * __builtin_amdgcn_logf(amplitudes[f]));
        const float rev = (frequencies[f] * d) * 0.15915494309189535f;
        const float s = a * __builtin_amdgcn_sinf(rev);
        const float c = a * __builtin_amdgcn_cosf(rev);

        const v4f r0 = c * a0 - s * a1;
        const v4f r1 = s * a0 + c * a1;
        __builtin_nontemporal_store(r0, &op[j * 512 + t]);
        __builtin_nontemporal_store(r1, &op[j * 512 + 256 + t]);

        a0 = n0;
        a1 = n1;
    }
}

extern "C" void kernel_launch(void* const* d_in, const int* in_sizes, int n_in,
                              void* d_out, int out_size, void* d_ws, size_t ws_size,
                              hipStream_t stream) {
    const float* x    = (const float*)d_in[0];
    const float* dt   = (const float*)d_in[1];
    const float* amp  = (const float*)d_in[2];
    const float* freq = (const float*)d_in[3];
    float* out = (float*)d_out;

    static_assert((Bn * Fn) % ITERS == 0, "grid divisibility");
    koopman_kernel<<<dim3(GRID), dim3(256), 0, stream>>>(x, dt, amp, freq, out);
}